// Round 1
// baseline (895.604 us; speedup 1.0000x reference)
//
#include <hip/hip_runtime.h>

// Problem constants (from reference):
#define CCH 3
#define HH 224
#define WW 220
#define NP 20          // num patches (4 x 5)
#define HID 32

#define W4     (WW / 4)            // 55 float4 per image row
#define IMG4   (CCH * HH * W4)     // 36960 float4 per image (591,360 B)
#define NT     512                 // threads per block (8 waves)
#define GPT    8                   // float4 per thread-chunk (128 B, line-aligned)
#define NGRP   (IMG4 / GPT)        // 4620 chunks per image
#define FULLIT (NGRP / NT)         // 9 full iterations
#define TAILT  (NGRP - FULLIT*NT)  // 12 tail chunks
#define INV_N  (1.0f / 7392.0f)    // 1 / (C*PH*PW)

typedef float v4f __attribute__((ext_vector_type(4)));

// Exact integer helpers (verified over the required ranges):
//   row = idx/55   : (idx*38131)>>21   exact for idx < 39568  (max 36959)
//   pr  = h/56     : (h*293)>>14       exact for h   < 683    (max 223)
//   pc  = c4/11    : (c4*94)>>10       exact for c4  < 103    (max 54)
__device__ __forceinline__ unsigned bin_of(unsigned idx, unsigned &c4, unsigned &pc)
{
    unsigned row = (idx * 38131u) >> 21;          // flat row 0..671
    c4 = idx - row * 55u;                         // float4 col 0..54
    unsigned h = row >= 224u ? row - 224u : row;  // h = row % 224
    h = h >= 224u ? h - 224u : h;
    unsigned pr = (h * 293u) >> 14;               // patch row 0..3
    pc = (c4 * 94u) >> 10;                        // patch col 0..4
    return pr * 5u + pc;
}

// One block per image, 512 threads. Each thread streams 128-B aligned chunks;
// a wave reads 8 KB contiguous; the block sweeps its 577.5-KB image linearly
// (the same access shape as a memset, which hits 80% of HBM peak here).
// Patch-sum accumulation goes to per-thread LDS slots bins[bin][tid]
// (bank = tid%32 -> 2 lanes/bank = conflict-free). Bin boundaries in the flat
// float4 index are >=11 apart, so an 8-float4 chunk crosses at most one
// boundary: split into two partial sums, two LDS RMWs per 128 B.
__global__ __launch_bounds__(NT) void fused_patch_nam_kernel(
    const float* __restrict__ x,
    const float* __restrict__ w1, const float* __restrict__ b1,
    const float* __restrict__ w2, const float* __restrict__ b2,
    float* __restrict__ out, int B)
{
    const int b   = blockIdx.x;
    const int tid = threadIdx.x;

    __shared__ float bins[NP * NT];               // 40 KiB -> up to 4 blocks/CU

    #pragma unroll
    for (int i = 0; i < NP; ++i) bins[i * NT + tid] = 0.f;
    __syncthreads();

    const v4f* img4 = (const v4f*)x + (size_t)b * IMG4;

    auto process = [&](unsigned g) {
        const unsigned idx0 = g * GPT;            // first float4 of chunk
        const v4f* p = img4 + idx0;
        v4f a[GPT];
        #pragma unroll
        for (int i = 0; i < GPT; ++i)             // 8 independent 16-B nt loads
            a[i] = __builtin_nontemporal_load(p + i);

        unsigned c40, pc0, c47, pc7;
        const unsigned bin0 = bin_of(idx0,             c40, pc0);
        const unsigned bin7 = bin_of(idx0 + (GPT - 1), c47, pc7);

        float v[GPT];
        #pragma unroll
        for (int i = 0; i < GPT; ++i)
            v[i] = (a[i].x + a[i].y) + (a[i].z + a[i].w);

        // next bin boundary after c40, in c4 units (55 == row wrap, also works)
        const unsigned nb = pc0 * 11u + 11u;
        float sa = v[0];            // elements before the boundary -> bin0
        float sb = v[GPT - 1];      // elements at/after boundary   -> bin7
        #pragma unroll
        for (int i = 1; i < GPT - 1; ++i) {
            const bool past = (c40 + (unsigned)i) >= nb;
            sa += past ? 0.f : v[i];
            sb += past ? v[i] : 0.f;
        }
        // If no boundary in the window, bin7 == bin0 and both RMWs hit the
        // same slot; per-wave DS ops are in-order, so this is still correct.
        bins[bin0 * NT + tid] += sa;
        bins[bin7 * NT + tid] += sb;
    };

    for (int it = 0; it < FULLIT; ++it)
        process((unsigned)(it * NT + tid));
    if (tid < TAILT)
        process((unsigned)(FULLIT * NT + tid));
    __syncthreads();

    // Reduce 512 partials per bin: wave w owns bins {w, w+8, w+16}.
    const int wid = tid >> 6, lane = tid & 63;
    float wsum0 = 0.f, wsum1 = 0.f, wsum2 = 0.f;
    {
        float s = 0.f;
        #pragma unroll
        for (int k = 0; k < 8; ++k) s += bins[wid * NT + lane + k * 64];
        #pragma unroll
        for (int off = 32; off >= 1; off >>= 1) s += __shfl_xor(s, off, 64);
        wsum0 = s;
    }
    {
        float s = 0.f;
        #pragma unroll
        for (int k = 0; k < 8; ++k) s += bins[(wid + 8) * NT + lane + k * 64];
        #pragma unroll
        for (int off = 32; off >= 1; off >>= 1) s += __shfl_xor(s, off, 64);
        wsum1 = s;
    }
    if (wid < 4) {
        float s = 0.f;
        #pragma unroll
        for (int k = 0; k < 8; ++k) s += bins[(wid + 16) * NT + lane + k * 64];
        #pragma unroll
        for (int off = 32; off >= 1; off >>= 1) s += __shfl_xor(s, off, 64);
        wsum2 = s;
    }
    __syncthreads();                 // all reads of bins[] done before reuse
    if (lane == 0) {
        bins[wid]     = wsum0;
        bins[wid + 8] = wsum1;
        if (wid < 4) bins[wid + 16] = wsum2;
    }
    __syncthreads();

    // Per-patch scalar MLP: relu(f*w1 + b1) . w2 + b2  (params L2-hot, 2.6 KB)
    if (tid < NP) {
        const float f = bins[tid] * INV_N;        // patch mean
        float acc = 0.f;
        #pragma unroll
        for (int k = 0; k < HID; ++k) {
            const float hh = fmaf(f, w1[tid * HID + k], b1[tid * HID + k]);
            acc = fmaf(fmaxf(hh, 0.f), w2[tid * HID + k], acc);
        }
        const float contrib = acc + b2[tid];
        out[B + (size_t)b * NP + tid] = contrib;  // contribs tail
        bins[64 + tid] = contrib;
    }
    __syncthreads();

    if (tid == 0) {
        float s = 0.f;
        #pragma unroll
        for (int p = 0; p < NP; ++p) s += bins[64 + p];
        out[b] = s;                               // score head
    }
}

extern "C" void kernel_launch(void* const* d_in, const int* in_sizes, int n_in,
                              void* d_out, int out_size, void* d_ws, size_t ws_size,
                              hipStream_t stream)
{
    const float* x  = (const float*)d_in[0];
    const float* w1 = (const float*)d_in[1];
    const float* b1 = (const float*)d_in[2];
    const float* w2 = (const float*)d_in[3];
    const float* b2 = (const float*)d_in[4];
    float* out = (float*)d_out;

    const int B = in_sizes[0] / (CCH * HH * WW);  // 1024

    fused_patch_nam_kernel<<<B, NT, 0, stream>>>(x, w1, b1, w2, b2, out, B);
}

// Round 2
// 723.727 us; speedup vs baseline: 1.2375x; 1.2375x over previous
//
#include <hip/hip_runtime.h>

// Problem constants (from reference):
#define CCH 3
#define HH 224
#define WW 220
#define NP 20          // num patches (4 x 5)
#define HID 32

#define W4     (WW / 4)            // 55 float4 per image row
#define IMG4   (CCH * HH * W4)     // 36960 float4 per image (591,360 B)
#define NT     512                 // threads per block (8 waves)
#define FULLIT (IMG4 / NT)         // 72 full iterations
#define TAILT  (IMG4 - FULLIT*NT)  // 96 tail elements
#define INV_N  (1.0f / 7392.0f)    // 1 / (C*PH*PW)

typedef float v4f __attribute__((ext_vector_type(4)));

// Exact integer helpers (verified over the required ranges):
//   row = idx/55 : (idx*38131)>>21  exact for idx < 39568 (max 36959)
//   pr  = h/56   : (h*293)>>14      exact for h   < 672   (max 223)
//   pc  = c4/11  : (c4*94)>>10      exact for c4  < 99    (max 54)
// A float4 never crosses a bin boundary: rows are 55 float4 (220/4) and a
// patch column is exactly 11 float4, so all 4 floats share one (row, pc).
__device__ __forceinline__ unsigned bin_of(unsigned idx)
{
    const unsigned row = (idx * 38131u) >> 21;     // flat row 0..671
    const unsigned c4  = idx - row * 55u;          // float4 col 0..54
    unsigned h = row;                              // h = row % 224
    h = h >= 448u ? h - 448u : (h >= 224u ? h - 224u : h);
    const unsigned pr = (h * 293u) >> 14;          // patch row 0..3
    const unsigned pc = (c4 * 94u) >> 10;          // patch col 0..4
    return pr * 5u + pc;
}

// One block per image, 512 threads, ONE forward-linear stream per block:
// iteration it -> lane reads img4[it*512 + tid]; a wave-load is 1 KB dense
// and 128-B aligned (16 B/lane, consecutive lanes). 1024 blocks = 1024
// linear streams (vs Round-0's ~32K scattered row-streams that thrashed
// DRAM row buffers at 1.7 TB/s; the 80%-of-peak fill is ~2K linear streams).
// Per-element patch bin via exact magic division; accumulate in per-thread
// LDS slots bins[bin][tid] (lane l and l+32 share a bank: 2-way = free).
__global__ __launch_bounds__(NT) void fused_patch_nam_kernel(
    const float* __restrict__ x,
    const float* __restrict__ w1, const float* __restrict__ b1,
    const float* __restrict__ w2, const float* __restrict__ b2,
    float* __restrict__ out, int B)
{
    const int b   = blockIdx.x;
    const int tid = threadIdx.x;

    __shared__ float bins[NP * NT];               // 40 KiB -> 4 blocks/CU exactly

    #pragma unroll
    for (int i = 0; i < NP; ++i) bins[i * NT + tid] = 0.f;
    __syncthreads();

    const v4f* img4 = (const v4f*)x + (size_t)b * IMG4;

    // Main sweep. unroll 4: loads are independent of the LDS RMWs (distinct
    // address spaces), so the scheduler keeps 4 wave-loads in flight while
    // the serialized same-slot DS read-modify-writes drain.
    #pragma unroll 4
    for (int it = 0; it < FULLIT; ++it) {
        const unsigned idx = (unsigned)(it * NT + tid);
        const v4f a = __builtin_nontemporal_load(img4 + idx);
        const unsigned bin = bin_of(idx);
        bins[bin * NT + tid] += (a.x + a.y) + (a.z + a.w);
    }
    if (tid < TAILT) {
        const unsigned idx = (unsigned)(FULLIT * NT + tid);
        const v4f a = __builtin_nontemporal_load(img4 + idx);
        const unsigned bin = bin_of(idx);
        bins[bin * NT + tid] += (a.x + a.y) + (a.z + a.w);
    }
    __syncthreads();

    // Reduce 512 partials per bin: wave w owns bins {w, w+8, w+16}.
    const int wid = tid >> 6, lane = tid & 63;
    float wsum0 = 0.f, wsum1 = 0.f, wsum2 = 0.f;
    {
        float s = 0.f;
        #pragma unroll
        for (int k = 0; k < 8; ++k) s += bins[wid * NT + lane + k * 64];
        #pragma unroll
        for (int off = 32; off >= 1; off >>= 1) s += __shfl_xor(s, off, 64);
        wsum0 = s;
    }
    {
        float s = 0.f;
        #pragma unroll
        for (int k = 0; k < 8; ++k) s += bins[(wid + 8) * NT + lane + k * 64];
        #pragma unroll
        for (int off = 32; off >= 1; off >>= 1) s += __shfl_xor(s, off, 64);
        wsum1 = s;
    }
    if (wid < 4) {
        float s = 0.f;
        #pragma unroll
        for (int k = 0; k < 8; ++k) s += bins[(wid + 16) * NT + lane + k * 64];
        #pragma unroll
        for (int off = 32; off >= 1; off >>= 1) s += __shfl_xor(s, off, 64);
        wsum2 = s;
    }
    __syncthreads();                 // all reads of bins[] done before reuse
    if (lane == 0) {
        bins[wid]     = wsum0;
        bins[wid + 8] = wsum1;
        if (wid < 4) bins[wid + 16] = wsum2;
    }
    __syncthreads();

    // Per-patch scalar MLP: relu(f*w1 + b1) . w2 + b2  (params L2-hot, 2.6 KB)
    if (tid < NP) {
        const float f = bins[tid] * INV_N;        // patch mean
        float acc = 0.f;
        #pragma unroll
        for (int k = 0; k < HID; ++k) {
            const float hh = fmaf(f, w1[tid * HID + k], b1[tid * HID + k]);
            acc = fmaf(fmaxf(hh, 0.f), w2[tid * HID + k], acc);
        }
        const float contrib = acc + b2[tid];
        out[B + (size_t)b * NP + tid] = contrib;  // contribs tail
        bins[64 + tid] = contrib;
    }
    __syncthreads();

    if (tid == 0) {
        float s = 0.f;
        #pragma unroll
        for (int p = 0; p < NP; ++p) s += bins[64 + p];
        out[b] = s;                               // score head
    }
}

extern "C" void kernel_launch(void* const* d_in, const int* in_sizes, int n_in,
                              void* d_out, int out_size, void* d_ws, size_t ws_size,
                              hipStream_t stream)
{
    const float* x  = (const float*)d_in[0];
    const float* w1 = (const float*)d_in[1];
    const float* b1 = (const float*)d_in[2];
    const float* w2 = (const float*)d_in[3];
    const float* b2 = (const float*)d_in[4];
    float* out = (float*)d_out;

    const int B = in_sizes[0] / (CCH * HH * WW);  // 1024

    fused_patch_nam_kernel<<<B, NT, 0, stream>>>(x, w1, b1, w2, b2, out, B);
}